// Round 2
// baseline (150.447 us; speedup 1.0000x reference)
//
#include <hip/hip_runtime.h>
#include <hip/hip_bf16.h>

typedef unsigned int u32;
typedef unsigned short u16;

#define TOKENS 512
#define OUT_F  8192
#define IN_F   4096
#define KPACK  (IN_F / 4)   // packed dwords per weight row (4 codes in low byte of each)

#define TM 128
#define TN 64
#define BK 64
#define LDK 72              // padded LDS row length (bf16 elems): 144 B, 16-B aligned

typedef __attribute__((ext_vector_type(8))) short bf16x8;
typedef __attribute__((ext_vector_type(4))) float f32x4;

// Pack two fp32 -> two bf16 (RNE) in one dword.
__device__ __forceinline__ u32 pack_bf16x2(float a, float b) {
    __hip_bfloat162 h = __float22bfloat162_rn(make_float2(a, b));
    union { __hip_bfloat162 h2; u32 u; } cvt;
    cvt.h2 = h;
    return cvt.u;
}

// Decode one packed dword (4 two-bit codes in the low byte) into two dwords,
// each holding two packed bf16 values.
// code 2 -> +1 (0x3F80), code 0 -> -1 (0xBF80), codes 1/3 -> (-)0.0.
__device__ __forceinline__ void decode4(u32 w, u32& lo, u32& hi) {
    u32 t = (w & 0xFFu) * 0x4001u;   // codes 0,1 at bit pairs [1:0],[17:16]
    u32 u = t >> 4;                  // codes 2,3 at bit pairs [1:0],[17:16]
    u32 nt = ~t;
    u32 nu = ~u;
    lo = ((nt & 0x10001u) * 0x3F80u) | ((nt & 0x20002u) << 14);
    hi = ((nu & 0x10001u) * 0x3F80u) | ((nu & 0x20002u) << 14);
}

__global__ __launch_bounds__(256, 2) void ternary_gemm(
    const float* __restrict__ X,           // [TOKENS, IN_F] fp32
    const u32* __restrict__ W2,            // [OUT_F, KPACK] packed codes
    const float* __restrict__ alpha,       // [OUT_F] fp32
    const float* __restrict__ bias,        // [OUT_F] fp32
    float* __restrict__ Out)               // [TOKENS, OUT_F] fp32
{
    __shared__ u16 As[TM * LDK];
    __shared__ u16 Bs[TN * LDK];

    const int tid  = threadIdx.x;
    const int lane = tid & 63;
    const int wave = tid >> 6;
    const int quad = lane >> 4;
    const int lr   = lane & 15;

    const int n0 = blockIdx.x * TN;
    const int m0 = blockIdx.y * TM;

    // 2x2 wave grid: each wave owns a 64x32 sub-tile of C
    const int wm = (wave >> 1) * 64;
    const int wn = (wave & 1) * 32;

    f32x4 acc[4][2];
#pragma unroll
    for (int i = 0; i < 4; ++i)
#pragma unroll
        for (int j = 0; j < 2; ++j)
            acc[i][j] = (f32x4){0.f, 0.f, 0.f, 0.f};

    // B staging assignment: thread t -> row bn, 16-code quarter bq
    const int bn = tid >> 2;
    const int bq = tid & 3;

    // A staging: thread handles 8 consecutive floats per r; 4 r's = 32 floats
    float4 aregs[8];
    uint4 breg;

    // Prologue: load K-step 0 into registers
#pragma unroll
    for (int r = 0; r < 4; ++r) {
        int idx = r * 256 + tid;
        int m = idx >> 3, c = idx & 7;
        const float* p = X + (m0 + m) * IN_F + c * 8;
        aregs[2 * r]     = *(const float4*)(p);
        aregs[2 * r + 1] = *(const float4*)(p + 4);
    }
    breg = *(const uint4*)(W2 + (n0 + bn) * KPACK + bq * 4);

    for (int ks = 0; ks < IN_F; ks += BK) {
        __syncthreads();   // previous iteration's frag reads complete

        // ---- convert + store staged A regs to LDS (padded rows) ----
#pragma unroll
        for (int r = 0; r < 4; ++r) {
            int idx = r * 256 + tid;
            int m = idx >> 3, c = idx & 7;
            float4 fa = aregs[2 * r], fb = aregs[2 * r + 1];
            uint4 q;
            q.x = pack_bf16x2(fa.x, fa.y);
            q.y = pack_bf16x2(fa.z, fa.w);
            q.z = pack_bf16x2(fb.x, fb.y);
            q.w = pack_bf16x2(fb.z, fb.w);
            *(uint4*)(As + m * LDK + c * 8) = q;
        }
        // ---- decode staged B reg -> 16 bf16 -> LDS ----
        {
            u32 w0 = breg.x, w1 = breg.y, w2v = breg.z, w3 = breg.w;
            u32 o0, o1, o2, o3, o4, o5, o6, o7;
            decode4(w0, o0, o1);
            decode4(w1, o2, o3);
            decode4(w2v, o4, o5);
            decode4(w3, o6, o7);
            uint4 lo = {o0, o1, o2, o3};
            uint4 hi = {o4, o5, o6, o7};
            *(uint4*)(Bs + bn * LDK + bq * 16)     = lo;
            *(uint4*)(Bs + bn * LDK + bq * 16 + 8) = hi;
        }

        // ---- prefetch next K-step into registers (overlaps with compute) ----
        if (ks + BK < IN_F) {
            int ks2 = ks + BK;
#pragma unroll
            for (int r = 0; r < 4; ++r) {
                int idx = r * 256 + tid;
                int m = idx >> 3, c = idx & 7;
                const float* p = X + (m0 + m) * IN_F + ks2 + c * 8;
                aregs[2 * r]     = *(const float4*)(p);
                aregs[2 * r + 1] = *(const float4*)(p + 4);
            }
            breg = *(const uint4*)(W2 + (n0 + bn) * KPACK + (ks2 >> 2) + bq * 4);
        }

        __syncthreads();   // staged tile visible

        // ---- MFMA over this K-step (two K=32 sub-iterations) ----
#pragma unroll
        for (int kk = 0; kk < 2; ++kk) {
            bf16x8 afrag[4], bfrag[2];
#pragma unroll
            for (int mt = 0; mt < 4; ++mt)
                afrag[mt] = *(const bf16x8*)(As + (wm + mt * 16 + lr) * LDK + kk * 32 + quad * 8);
#pragma unroll
            for (int nt = 0; nt < 2; ++nt)
                bfrag[nt] = *(const bf16x8*)(Bs + (wn + nt * 16 + lr) * LDK + kk * 32 + quad * 8);
#pragma unroll
            for (int mt = 0; mt < 4; ++mt)
#pragma unroll
                for (int nt = 0; nt < 2; ++nt)
                    acc[mt][nt] = __builtin_amdgcn_mfma_f32_16x16x32_bf16(
                        afrag[mt], bfrag[nt], acc[mt][nt], 0, 0, 0);
        }
    }

    // ---- epilogue: alpha * acc + bias, store fp32 ----
#pragma unroll
    for (int nt = 0; nt < 2; ++nt) {
        int ncol = n0 + wn + nt * 16 + lr;
        float av = alpha[ncol];
        float bv = bias[ncol];
#pragma unroll
        for (int mt = 0; mt < 4; ++mt) {
            int mbase = m0 + wm + mt * 16 + quad * 4;
#pragma unroll
            for (int r = 0; r < 4; ++r) {
                Out[(mbase + r) * OUT_F + ncol] = acc[mt][nt][r] * av + bv;
            }
        }
    }
}

extern "C" void kernel_launch(void* const* d_in, const int* in_sizes, int n_in,
                              void* d_out, int out_size, void* d_ws, size_t ws_size,
                              hipStream_t stream) {
    const float* x = (const float*)d_in[0];
    const u32* w2 = (const u32*)d_in[1];
    const float* alpha = (const float*)d_in[2];
    const float* bias  = (const float*)d_in[3];
    float* out = (float*)d_out;

    dim3 grid(OUT_F / TN, TOKENS / TM);   // 128 x 4 = 512 blocks, 2 per CU
    ternary_gemm<<<grid, 256, 0, stream>>>(x, w2, alpha, bias, out);
}